// Round 6
// baseline (356.532 us; speedup 1.0000x reference)
//
#include <hip/hip_runtime.h>
#include <hip/hip_fp16.h>

// Texture pyramid bilinear sampling. All 3 output channels are the SAME
// pyramid1 sum -> compute once, write 3 planes.
//
// Supertexture: the 4-level sum is piecewise bilinear on a single 2048^2 cell
// grid -> precompute node values at 2049^2 grid points, pack each cell's 4
// corners as fp16x4 (uint2), main kernel does ONE scattered 8B load per pixel.
//
// Main kernel is at the random-fill roofline (~3.8 TB/s L2-miss fill path,
// invariant to ILP; rounds 3&5 within 1%). Round-6: cut the build-phase
// overhead (~30us) with two fully-coalesced passes instead of scattered 2B
// stores: (A) node plane fp16, (B) plane -> quad transform.

typedef float f32x4 __attribute__((ext_vector_type(4)));

// ---------- exact f32 sampler (zero padding) --------------------------------
template <int N>
__device__ __forceinline__ float sample_level(const float* __restrict__ t,
                                              float gx, float gy) {
    float ix = ((gx + 1.0f) * (float)N - 1.0f) * 0.5f;
    float iy = ((gy + 1.0f) * (float)N - 1.0f) * 0.5f;
    float x0f = floorf(ix), y0f = floorf(iy);
    float wx1 = ix - x0f, wy1 = iy - y0f;
    float wx0 = 1.0f - wx1, wy0 = 1.0f - wy1;
    int x0 = (int)x0f, y0 = (int)y0f;
    bool vx0 = (x0 >= 0) & (x0 <= N - 1);
    bool vx1 = (x0 >= -1) & (x0 <= N - 2);
    bool vy0 = (y0 >= 0) & (y0 <= N - 1);
    bool vy1 = (y0 >= -1) & (y0 <= N - 2);
    int x0c = min(max(x0, 0), N - 1), x1c = min(max(x0 + 1, 0), N - 1);
    int y0c = min(max(y0, 0), N - 1), y1c = min(max(y0 + 1, 0), N - 1);
    const float* r0 = t + y0c * N;
    const float* r1 = t + y1c * N;
    float v00 = (vx0 & vy0) ? r0[x0c] : 0.0f;
    float v10 = (vx1 & vy0) ? r0[x1c] : 0.0f;
    float v01 = (vx0 & vy1) ? r1[x0c] : 0.0f;
    float v11 = (vx1 & vy1) ? r1[x1c] : 0.0f;
    return wx0 * wy0 * v00 + wx1 * wy0 * v10 + wx0 * wy1 * v01 + wx1 * wy1 * v11;
}

__device__ __forceinline__ float eval_F(const float* __restrict__ l1,
                                        const float* __restrict__ l2,
                                        const float* __restrict__ l3,
                                        const float* __restrict__ l4,
                                        int i, int j) {
    const float gx = (float)(i - 1024) * (1.0f / 1024.0f);
    const float gy = (float)(j - 1024) * (1.0f / 1024.0f);
    return sample_level<1024>(l1, gx, gy)
         + sample_level< 512>(l2, gx, gy)
         + sample_level< 256>(l3, gx, gy)
         + sample_level< 128>(l4, gx, gy);
}

// ---------- build, two-pass coalesced ---------------------------------------
// Pass A: node plane fp16, row stride 2056 (16B-aligned rows).
constexpr int PLANE_STRIDE = 2056;

__global__ __launch_bounds__(256) void node_plane_kernel(
    const float* __restrict__ l1, const float* __restrict__ l2,
    const float* __restrict__ l3, const float* __restrict__ l4,
    unsigned short* __restrict__ plane)
{
    const int idx = blockIdx.x * 256 + threadIdx.x;
    if (idx >= 2049 * 2049) return;
    const int j = idx / 2049;
    const int i = idx - j * 2049;
    const float f = eval_F(l1, l2, l3, l4, i, j);
    plane[(size_t)j * PLANE_STRIDE + i] = __half_as_ushort(__float2half(f));
}

// Pass B: quads. Cell (j0,i0): slots {n(i0,j0), n(i0+1,j0), n(i0,j0+1),
// n(i0+1,j0+1)} = {q.x lo, q.x hi, q.y lo, q.y hi}.
__global__ __launch_bounds__(256) void plane_to_quads_kernel(
    const unsigned short* __restrict__ plane,
    uint2* __restrict__ Q)
{
    const int idx = blockIdx.x * 256 + threadIdx.x;   // < 2048*2048
    const int j0 = idx >> 11;
    const int i0 = idx & 2047;
    const unsigned short* r0 = plane + (size_t)j0 * PLANE_STRIDE + i0;
    const unsigned short* r1 = r0 + PLANE_STRIDE;
    uint2 q;
    q.x = (unsigned)r0[0] | ((unsigned)r0[1] << 16);
    q.y = (unsigned)r1[0] | ((unsigned)r1[1] << 16);
    Q[idx] = q;
}

// ---------- fallback single-pass build (scattered stores) -------------------
__global__ __launch_bounds__(256) void build_nodes_kernel(
    const float* __restrict__ l1, const float* __restrict__ l2,
    const float* __restrict__ l3, const float* __restrict__ l4,
    unsigned short* __restrict__ Qs)
{
    const int idx = blockIdx.x * 256 + threadIdx.x;
    if (idx >= 2049 * 2049) return;
    const int j = idx / 2049;
    const int i = idx - j * 2049;
    const float f = eval_F(l1, l2, l3, l4, i, j);
    const unsigned short h = __half_as_ushort(__float2half(f));
    const bool iL = (i < 2048), iR = (i > 0);
    const bool jT = (j < 2048), jB = (j > 0);
    if (iL & jT) Qs[((size_t)(j * 2048 + i) << 2) + 0] = h;
    if (iR & jT) Qs[((size_t)(j * 2048 + i - 1) << 2) + 1] = h;
    if (iL & jB) Qs[((size_t)((j - 1) * 2048 + i) << 2) + 2] = h;
    if (iR & jB) Qs[((size_t)((j - 1) * 2048 + i - 1) << 2) + 3] = h;
}

// ---------- main: 4 pixels per thread ---------------------------------------
__device__ __forceinline__ float sample_super(const uint2* __restrict__ Q,
                                              float u, float v) {
    float iu = u * 2048.0f;
    float iv = v * 2048.0f;
    float fu = floorf(iu), fv = floorf(iv);
    int i0 = min(max((int)fu, 0), 2047);
    int j0 = min(max((int)fv, 0), 2047);
    float wx = iu - fu, wy = iv - fv;
    uint2 q = Q[((size_t)j0 << 11) + i0];
    float v00 = __half2float(__ushort_as_half((unsigned short)(q.x & 0xffffu)));
    float v10 = __half2float(__ushort_as_half((unsigned short)(q.x >> 16)));
    float v01 = __half2float(__ushort_as_half((unsigned short)(q.y & 0xffffu)));
    float v11 = __half2float(__ushort_as_half((unsigned short)(q.y >> 16)));
    float r0 = fmaf(wx, v10 - v00, v00);
    float r1 = fmaf(wx, v11 - v01, v01);
    return fmaf(wy, r1 - r0, r0);
}

__global__ __launch_bounds__(256) void texture_super4_kernel(
    const f32x4* __restrict__ x,    // 2 pixels (gx,gy pairs) per f32x4
    const uint2* __restrict__ Q,    // 2048^2 quads of 4 fp16
    float* __restrict__ out)
{
    const int t = blockIdx.x * 256 + threadIdx.x;   // 4 pixels per thread
    const int p = t << 2;

    f32x4 c01 = __builtin_nontemporal_load(&x[(size_t)t * 2]);
    f32x4 c23 = __builtin_nontemporal_load(&x[(size_t)t * 2 + 1]);

    float y0 = sample_super(Q, c01.x, c01.y);
    float y1 = sample_super(Q, c01.z, c01.w);
    float y2 = sample_super(Q, c23.x, c23.y);
    float y3 = sample_super(Q, c23.z, c23.w);

    const int b   = p >> 20;                 // HO*WO = 2^20
    const int rem = p & ((1 << 20) - 1);
    float* o = out + ((size_t)(b * 3) << 20) + rem;
    f32x4 v = { y0, y1, y2, y3 };
    __builtin_nontemporal_store(v, (f32x4*)(o));
    __builtin_nontemporal_store(v, (f32x4*)(o + ((size_t)1 << 20)));
    __builtin_nontemporal_store(v, (f32x4*)(o + ((size_t)2 << 20)));
}

// ---------- last-resort fallback: direct f32 sampling -----------------------
__global__ __launch_bounds__(256) void texture_pyramid_kernel(
    const float2* __restrict__ x,
    const float* __restrict__ l1, const float* __restrict__ l2,
    const float* __restrict__ l3, const float* __restrict__ l4,
    float* __restrict__ out)
{
    const int p = blockIdx.x * 256 + threadIdx.x;
    float2 g = x[p];
    float gx = g.x * 2.0f - 1.0f;
    float gy = g.y * 2.0f - 1.0f;
    float y = sample_level<1024>(l1, gx, gy) + sample_level<512>(l2, gx, gy)
            + sample_level<256>(l3, gx, gy) + sample_level<128>(l4, gx, gy);
    const int b = p >> 20;
    const int rem = p & ((1 << 20) - 1);
    float* o = out + ((size_t)(b * 3) << 20) + rem;
    o[0] = y; o[(size_t)1 << 20] = y; o[(size_t)2 << 20] = y;
}
// ----------------------------------------------------------------------------

extern "C" void kernel_launch(void* const* d_in, const int* in_sizes, int n_in,
                              void* d_out, int out_size, void* d_ws, size_t ws_size,
                              hipStream_t stream) {
    const float* l1 = (const float*)d_in[1];
    const float* l2 = (const float*)d_in[2];
    const float* l3 = (const float*)d_in[3];
    const float* l4 = (const float*)d_in[4];
    float* out = (float*)d_out;

    const int total_pixels = 16 * 1024 * 1024;            // 2^24
    const size_t quad_bytes  = 2048ull * 2048ull * 8ull;  // 33.55 MB
    const size_t plane_bytes = 2049ull * PLANE_STRIDE * 2ull; // 8.43 MB
    const size_t need_two_pass = quad_bytes + plane_bytes;    // ~42 MB

    const int nodes = 2049 * 2049;
    const int cells = 2048 * 2048;

    if (ws_size >= need_two_pass) {
        uint2* Q = (uint2*)d_ws;
        unsigned short* plane =
            (unsigned short*)((char*)d_ws + quad_bytes);
        node_plane_kernel<<<(nodes + 255) / 256, 256, 0, stream>>>(
            l1, l2, l3, l4, plane);
        plane_to_quads_kernel<<<cells / 256, 256, 0, stream>>>(plane, Q);
        texture_super4_kernel<<<(total_pixels / 4) / 256, 256, 0, stream>>>(
            (const f32x4*)d_in[0], (const uint2*)Q, out);
    } else if (ws_size >= quad_bytes) {
        unsigned short* Qs = (unsigned short*)d_ws;
        build_nodes_kernel<<<(nodes + 255) / 256, 256, 0, stream>>>(
            l1, l2, l3, l4, Qs);
        texture_super4_kernel<<<(total_pixels / 4) / 256, 256, 0, stream>>>(
            (const f32x4*)d_in[0], (const uint2*)d_ws, out);
    } else {
        texture_pyramid_kernel<<<total_pixels / 256, 256, 0, stream>>>(
            (const float2*)d_in[0], l1, l2, l3, l4, out);
    }
}

// Round 7
// 352.952 us; speedup vs baseline: 1.0101x; 1.0101x over previous
//
#include <hip/hip_runtime.h>
#include <hip/hip_fp16.h>

// Texture pyramid bilinear sampling. All 3 output channels are the SAME
// pyramid1 sum -> compute once, write 3 planes.
//
// Supertexture: the 4-level sum is piecewise bilinear on a single 2048^2 cell
// grid -> precompute node values at 2049^2 grid points, pack each cell's 4
// corners as fp16x4 (uint2), main kernel does ONE scattered 8B load per pixel.
//
// Main kernel is at the random-fill roofline (~3.8 TB/s L2-miss fill path;
// invariant to ILP and nt-hints across rounds 3/5/6). Round-7: replace the
// scatter-store build (~30us, 16.8M scalar 2B stores) with an LDS-tiled build:
// each block evals a 17x17 node halo into LDS, then writes 16x16 cells as
// coalesced 8B quad stores.

typedef float f32x4 __attribute__((ext_vector_type(4)));

// ---------- exact f32 sampler (zero padding) --------------------------------
template <int N>
__device__ __forceinline__ float sample_level(const float* __restrict__ t,
                                              float gx, float gy) {
    float ix = ((gx + 1.0f) * (float)N - 1.0f) * 0.5f;
    float iy = ((gy + 1.0f) * (float)N - 1.0f) * 0.5f;
    float x0f = floorf(ix), y0f = floorf(iy);
    float wx1 = ix - x0f, wy1 = iy - y0f;
    float wx0 = 1.0f - wx1, wy0 = 1.0f - wy1;
    int x0 = (int)x0f, y0 = (int)y0f;
    bool vx0 = (x0 >= 0) & (x0 <= N - 1);
    bool vx1 = (x0 >= -1) & (x0 <= N - 2);
    bool vy0 = (y0 >= 0) & (y0 <= N - 1);
    bool vy1 = (y0 >= -1) & (y0 <= N - 2);
    int x0c = min(max(x0, 0), N - 1), x1c = min(max(x0 + 1, 0), N - 1);
    int y0c = min(max(y0, 0), N - 1), y1c = min(max(y0 + 1, 0), N - 1);
    const float* r0 = t + y0c * N;
    const float* r1 = t + y1c * N;
    float v00 = (vx0 & vy0) ? r0[x0c] : 0.0f;
    float v10 = (vx1 & vy0) ? r0[x1c] : 0.0f;
    float v01 = (vx0 & vy1) ? r1[x0c] : 0.0f;
    float v11 = (vx1 & vy1) ? r1[x1c] : 0.0f;
    return wx0 * wy0 * v00 + wx1 * wy0 * v10 + wx0 * wy1 * v01 + wx1 * wy1 * v11;
}

__device__ __forceinline__ float eval_F(const float* __restrict__ l1,
                                        const float* __restrict__ l2,
                                        const float* __restrict__ l3,
                                        const float* __restrict__ l4,
                                        int i, int j) {
    const float gx = (float)(i - 1024) * (1.0f / 1024.0f);
    const float gy = (float)(j - 1024) * (1.0f / 1024.0f);
    return sample_level<1024>(l1, gx, gy)
         + sample_level< 512>(l2, gx, gy)
         + sample_level< 256>(l3, gx, gy)
         + sample_level< 128>(l4, gx, gy);
}

// ---------- LDS-tiled build -------------------------------------------------
// Block = 256 threads = 16x16 cells. Needs 17x17 node halo in LDS.
// Quad for cell (cy,cx): {n(cx,cy), n(cx+1,cy), n(cx,cy+1), n(cx+1,cy+1)}.
__global__ __launch_bounds__(256) void build_quads_tiled_kernel(
    const float* __restrict__ l1, const float* __restrict__ l2,
    const float* __restrict__ l3, const float* __restrict__ l4,
    uint2* __restrict__ Q)
{
    __shared__ unsigned short n[17 * 17];
    const int bx = blockIdx.x & 127;       // 128x128 blocks of 16x16 cells
    const int by = blockIdx.x >> 7;
    const int tid = threadIdx.x;

    // evaluate 17x17 nodes: idx = lj*17 + li; global node (bx*16+li, by*16+lj)
    {
        int idx = tid;
        int lj = idx / 17, li = idx - lj * 17;
        float f = eval_F(l1, l2, l3, l4, bx * 16 + li, by * 16 + lj);
        n[idx] = __half_as_ushort(__float2half(f));
        idx = tid + 256;
        if (idx < 289) {
            lj = idx / 17; li = idx - lj * 17;
            f = eval_F(l1, l2, l3, l4, bx * 16 + li, by * 16 + lj);
            n[idx] = __half_as_ushort(__float2half(f));
        }
    }
    __syncthreads();

    const int ty = tid >> 4, tx = tid & 15;
    uint2 q;
    q.x = (unsigned)n[ty * 17 + tx]       | ((unsigned)n[ty * 17 + tx + 1] << 16);
    q.y = (unsigned)n[(ty + 1) * 17 + tx] | ((unsigned)n[(ty + 1) * 17 + tx + 1] << 16);
    const int cy = by * 16 + ty, cx = bx * 16 + tx;
    Q[((size_t)cy << 11) + cx] = q;        // coalesced 8B stores
}

// ---------- main: 4 pixels per thread ---------------------------------------
__device__ __forceinline__ float sample_super(const uint2* __restrict__ Q,
                                              float u, float v) {
    float iu = u * 2048.0f;
    float iv = v * 2048.0f;
    float fu = floorf(iu), fv = floorf(iv);
    int i0 = min(max((int)fu, 0), 2047);
    int j0 = min(max((int)fv, 0), 2047);
    float wx = iu - fu, wy = iv - fv;
    uint2 q = Q[((size_t)j0 << 11) + i0];
    float v00 = __half2float(__ushort_as_half((unsigned short)(q.x & 0xffffu)));
    float v10 = __half2float(__ushort_as_half((unsigned short)(q.x >> 16)));
    float v01 = __half2float(__ushort_as_half((unsigned short)(q.y & 0xffffu)));
    float v11 = __half2float(__ushort_as_half((unsigned short)(q.y >> 16)));
    float r0 = fmaf(wx, v10 - v00, v00);
    float r1 = fmaf(wx, v11 - v01, v01);
    return fmaf(wy, r1 - r0, r0);
}

__global__ __launch_bounds__(256) void texture_super4_kernel(
    const f32x4* __restrict__ x,    // 2 pixels (gx,gy pairs) per f32x4
    const uint2* __restrict__ Q,    // 2048^2 quads of 4 fp16
    float* __restrict__ out)
{
    const int t = blockIdx.x * 256 + threadIdx.x;   // 4 pixels per thread
    const int p = t << 2;

    f32x4 c01 = __builtin_nontemporal_load(&x[(size_t)t * 2]);
    f32x4 c23 = __builtin_nontemporal_load(&x[(size_t)t * 2 + 1]);

    float y0 = sample_super(Q, c01.x, c01.y);
    float y1 = sample_super(Q, c01.z, c01.w);
    float y2 = sample_super(Q, c23.x, c23.y);
    float y3 = sample_super(Q, c23.z, c23.w);

    const int b   = p >> 20;                 // HO*WO = 2^20
    const int rem = p & ((1 << 20) - 1);
    float* o = out + ((size_t)(b * 3) << 20) + rem;
    f32x4 v = { y0, y1, y2, y3 };
    __builtin_nontemporal_store(v, (f32x4*)(o));
    __builtin_nontemporal_store(v, (f32x4*)(o + ((size_t)1 << 20)));
    __builtin_nontemporal_store(v, (f32x4*)(o + ((size_t)2 << 20)));
}

// ---------- last-resort fallback: direct f32 sampling -----------------------
__global__ __launch_bounds__(256) void texture_pyramid_kernel(
    const float2* __restrict__ x,
    const float* __restrict__ l1, const float* __restrict__ l2,
    const float* __restrict__ l3, const float* __restrict__ l4,
    float* __restrict__ out)
{
    const int p = blockIdx.x * 256 + threadIdx.x;
    float2 g = x[p];
    float gx = g.x * 2.0f - 1.0f;
    float gy = g.y * 2.0f - 1.0f;
    float y = sample_level<1024>(l1, gx, gy) + sample_level<512>(l2, gx, gy)
            + sample_level<256>(l3, gx, gy) + sample_level<128>(l4, gx, gy);
    const int b = p >> 20;
    const int rem = p & ((1 << 20) - 1);
    float* o = out + ((size_t)(b * 3) << 20) + rem;
    o[0] = y; o[(size_t)1 << 20] = y; o[(size_t)2 << 20] = y;
}
// ----------------------------------------------------------------------------

extern "C" void kernel_launch(void* const* d_in, const int* in_sizes, int n_in,
                              void* d_out, int out_size, void* d_ws, size_t ws_size,
                              hipStream_t stream) {
    const float* l1 = (const float*)d_in[1];
    const float* l2 = (const float*)d_in[2];
    const float* l3 = (const float*)d_in[3];
    const float* l4 = (const float*)d_in[4];
    float* out = (float*)d_out;

    const int total_pixels = 16 * 1024 * 1024;            // 2^24
    const size_t quad_bytes = 2048ull * 2048ull * 8ull;   // 33.55 MB

    if (ws_size >= quad_bytes) {
        uint2* Q = (uint2*)d_ws;
        build_quads_tiled_kernel<<<128 * 128, 256, 0, stream>>>(
            l1, l2, l3, l4, Q);
        texture_super4_kernel<<<(total_pixels / 4) / 256, 256, 0, stream>>>(
            (const f32x4*)d_in[0], (const uint2*)Q, out);
    } else {
        texture_pyramid_kernel<<<total_pixels / 256, 256, 0, stream>>>(
            (const float2*)d_in[0], l1, l2, l3, l4, out);
    }
}

// Round 8
// 340.507 us; speedup vs baseline: 1.0471x; 1.0365x over previous
//
#include <hip/hip_runtime.h>
#include <hip/hip_fp16.h>

// Texture pyramid bilinear sampling. All 3 output channels are the SAME
// pyramid1 sum -> compute once, write 3 planes.
//
// Supertexture: the 4-level sum is piecewise bilinear on a single 2048^2 cell
// grid -> precompute node values at 2049^2 grid points, pack each cell's 4
// corners as fp16x4 (uint2), main kernel does ONE scattered 8B load per pixel.
// Main kernel is at the random-fill roofline (~3.8 TB/s L2-miss fill path;
// invariant across rounds 3/5/6/7).
//
// Round-8: separable build. On the node grid, each level's bilinear sample has
// fixed 2-tap weights per axis (ix = i/s - 0.5). Each block loads the 4 tiny
// level patches (161 floats total) into LDS once, evaluates its 17x17 nodes
// from LDS (zero-padding = zero-filled OOB patch entries), then emits 16x16
// quads coalesced. Replaces ~76M scattered eval loads with ~3M patch loads.

typedef float f32x4 __attribute__((ext_vector_type(4)));

// ---------- exact f32 sampler (zero padding) — fallback path only -----------
template <int N>
__device__ __forceinline__ float sample_level(const float* __restrict__ t,
                                              float gx, float gy) {
    float ix = ((gx + 1.0f) * (float)N - 1.0f) * 0.5f;
    float iy = ((gy + 1.0f) * (float)N - 1.0f) * 0.5f;
    float x0f = floorf(ix), y0f = floorf(iy);
    float wx1 = ix - x0f, wy1 = iy - y0f;
    float wx0 = 1.0f - wx1, wy0 = 1.0f - wy1;
    int x0 = (int)x0f, y0 = (int)y0f;
    bool vx0 = (x0 >= 0) & (x0 <= N - 1);
    bool vx1 = (x0 >= -1) & (x0 <= N - 2);
    bool vy0 = (y0 >= 0) & (y0 <= N - 1);
    bool vy1 = (y0 >= -1) & (y0 <= N - 2);
    int x0c = min(max(x0, 0), N - 1), x1c = min(max(x0 + 1, 0), N - 1);
    int y0c = min(max(y0, 0), N - 1), y1c = min(max(y0 + 1, 0), N - 1);
    const float* r0 = t + y0c * N;
    const float* r1 = t + y1c * N;
    float v00 = (vx0 & vy0) ? r0[x0c] : 0.0f;
    float v10 = (vx1 & vy0) ? r0[x1c] : 0.0f;
    float v01 = (vx0 & vy1) ? r1[x0c] : 0.0f;
    float v11 = (vx1 & vy1) ? r1[x1c] : 0.0f;
    return wx0 * wy0 * v00 + wx1 * wy0 * v10 + wx0 * wy1 * v01 + wx1 * wy1 * v11;
}

// ---------- separable LDS build ---------------------------------------------
// Block = 256 threads = one 16x16-cell tile (17x17 nodes).
// Level with scale S (=2048/N): node i -> ix = i/S - 0.5; x0 = floor(ix);
// taps (x0, x0+1), weights (1-w, w), w = ix - x0. Patch texel range for the
// tile: [16*bx/S - 1, 16*bx/S + 16/S]  -> width W = 16/S + 2.

template <int S>
__device__ __forceinline__ void load_patch(const float* __restrict__ t,
                                           float* __restrict__ P,
                                           int bx, int by, int tid) {
    constexpr int N = 2048 / S;
    constexpr int W = 16 / S + 2;
    if (tid < W * W) {
        const int ly = tid / W, lx = tid - ly * W;
        const int gx = (16 / S) * bx - 1 + lx;
        const int gy = (16 / S) * by - 1 + ly;
        const bool v = ((unsigned)gx < (unsigned)N) & ((unsigned)gy < (unsigned)N);
        P[tid] = v ? t[(size_t)gy * N + gx] : 0.0f;
    }
}

template <int S>
__device__ __forceinline__ float eval_patch(const float* __restrict__ P,
                                            int di, int dj) {
    constexpr int W = 16 / S + 2;
    const float tx = (float)di * (1.0f / (float)S) - 0.5f;
    const float ty = (float)dj * (1.0f / (float)S) - 0.5f;
    const float fx = floorf(tx), fy = floorf(ty);
    const float wx1 = tx - fx, wy1 = ty - fy;
    const int lx = (int)fx + 1;
    const int ly = (int)fy + 1;
    const float* r0 = P + ly * W + lx;
    const float* r1 = r0 + W;
    const float h0 = fmaf(wx1, r0[1] - r0[0], r0[0]);
    const float h1 = fmaf(wx1, r1[1] - r1[0], r1[0]);
    return fmaf(wy1, h1 - h0, h0);
}

__global__ __launch_bounds__(256) void build_quads_sep_kernel(
    const float* __restrict__ l1, const float* __restrict__ l2,
    const float* __restrict__ l3, const float* __restrict__ l4,
    uint2* __restrict__ Q)
{
    __shared__ float P1[10 * 10];
    __shared__ float P2[6 * 6];
    __shared__ float P3[4 * 4];
    __shared__ float P4[3 * 3];
    __shared__ unsigned short n[17 * 17];

    const int bx = blockIdx.x & 127;      // 128x128 tiles
    const int by = blockIdx.x >> 7;
    const int tid = threadIdx.x;

    load_patch< 2>(l1, P1, bx, by, tid);
    load_patch< 4>(l2, P2, bx, by, tid);
    load_patch< 8>(l3, P3, bx, by, tid);
    load_patch<16>(l4, P4, bx, by, tid);
    __syncthreads();

    // evaluate 17x17 nodes from the LDS patches
    {
        int idx = tid;
        int dj = idx / 17, di = idx - dj * 17;
        float f = eval_patch< 2>(P1, di, dj) + eval_patch< 4>(P2, di, dj)
                + eval_patch< 8>(P3, di, dj) + eval_patch<16>(P4, di, dj);
        n[idx] = __half_as_ushort(__float2half(f));
        idx = tid + 256;
        if (idx < 289) {
            dj = idx / 17; di = idx - dj * 17;
            f = eval_patch< 2>(P1, di, dj) + eval_patch< 4>(P2, di, dj)
              + eval_patch< 8>(P3, di, dj) + eval_patch<16>(P4, di, dj);
            n[idx] = __half_as_ushort(__float2half(f));
        }
    }
    __syncthreads();

    const int ty = tid >> 4, tx = tid & 15;
    uint2 q;
    q.x = (unsigned)n[ty * 17 + tx]       | ((unsigned)n[ty * 17 + tx + 1] << 16);
    q.y = (unsigned)n[(ty + 1) * 17 + tx] | ((unsigned)n[(ty + 1) * 17 + tx + 1] << 16);
    const int cy = by * 16 + ty, cx = bx * 16 + tx;
    Q[((size_t)cy << 11) + cx] = q;        // coalesced 8B stores
}

// ---------- main: 4 pixels per thread ---------------------------------------
__device__ __forceinline__ float sample_super(const uint2* __restrict__ Q,
                                              float u, float v) {
    float iu = u * 2048.0f;
    float iv = v * 2048.0f;
    float fu = floorf(iu), fv = floorf(iv);
    int i0 = min(max((int)fu, 0), 2047);
    int j0 = min(max((int)fv, 0), 2047);
    float wx = iu - fu, wy = iv - fv;
    uint2 q = Q[((size_t)j0 << 11) + i0];
    float v00 = __half2float(__ushort_as_half((unsigned short)(q.x & 0xffffu)));
    float v10 = __half2float(__ushort_as_half((unsigned short)(q.x >> 16)));
    float v01 = __half2float(__ushort_as_half((unsigned short)(q.y & 0xffffu)));
    float v11 = __half2float(__ushort_as_half((unsigned short)(q.y >> 16)));
    float r0 = fmaf(wx, v10 - v00, v00);
    float r1 = fmaf(wx, v11 - v01, v01);
    return fmaf(wy, r1 - r0, r0);
}

__global__ __launch_bounds__(256) void texture_super4_kernel(
    const f32x4* __restrict__ x,    // 2 pixels (gx,gy pairs) per f32x4
    const uint2* __restrict__ Q,    // 2048^2 quads of 4 fp16
    float* __restrict__ out)
{
    const int t = blockIdx.x * 256 + threadIdx.x;   // 4 pixels per thread
    const int p = t << 2;

    f32x4 c01 = __builtin_nontemporal_load(&x[(size_t)t * 2]);
    f32x4 c23 = __builtin_nontemporal_load(&x[(size_t)t * 2 + 1]);

    float y0 = sample_super(Q, c01.x, c01.y);
    float y1 = sample_super(Q, c01.z, c01.w);
    float y2 = sample_super(Q, c23.x, c23.y);
    float y3 = sample_super(Q, c23.z, c23.w);

    const int b   = p >> 20;                 // HO*WO = 2^20
    const int rem = p & ((1 << 20) - 1);
    float* o = out + ((size_t)(b * 3) << 20) + rem;
    f32x4 v = { y0, y1, y2, y3 };
    __builtin_nontemporal_store(v, (f32x4*)(o));
    __builtin_nontemporal_store(v, (f32x4*)(o + ((size_t)1 << 20)));
    __builtin_nontemporal_store(v, (f32x4*)(o + ((size_t)2 << 20)));
}

// ---------- last-resort fallback: direct f32 sampling -----------------------
__global__ __launch_bounds__(256) void texture_pyramid_kernel(
    const float2* __restrict__ x,
    const float* __restrict__ l1, const float* __restrict__ l2,
    const float* __restrict__ l3, const float* __restrict__ l4,
    float* __restrict__ out)
{
    const int p = blockIdx.x * 256 + threadIdx.x;
    float2 g = x[p];
    float gx = g.x * 2.0f - 1.0f;
    float gy = g.y * 2.0f - 1.0f;
    float y = sample_level<1024>(l1, gx, gy) + sample_level<512>(l2, gx, gy)
            + sample_level<256>(l3, gx, gy) + sample_level<128>(l4, gx, gy);
    const int b = p >> 20;
    const int rem = p & ((1 << 20) - 1);
    float* o = out + ((size_t)(b * 3) << 20) + rem;
    o[0] = y; o[(size_t)1 << 20] = y; o[(size_t)2 << 20] = y;
}
// ----------------------------------------------------------------------------

extern "C" void kernel_launch(void* const* d_in, const int* in_sizes, int n_in,
                              void* d_out, int out_size, void* d_ws, size_t ws_size,
                              hipStream_t stream) {
    const float* l1 = (const float*)d_in[1];
    const float* l2 = (const float*)d_in[2];
    const float* l3 = (const float*)d_in[3];
    const float* l4 = (const float*)d_in[4];
    float* out = (float*)d_out;

    const int total_pixels = 16 * 1024 * 1024;            // 2^24
    const size_t quad_bytes = 2048ull * 2048ull * 8ull;   // 33.55 MB

    if (ws_size >= quad_bytes) {
        uint2* Q = (uint2*)d_ws;
        build_quads_sep_kernel<<<128 * 128, 256, 0, stream>>>(
            l1, l2, l3, l4, Q);
        texture_super4_kernel<<<(total_pixels / 4) / 256, 256, 0, stream>>>(
            (const f32x4*)d_in[0], (const uint2*)Q, out);
    } else {
        texture_pyramid_kernel<<<total_pixels / 256, 256, 0, stream>>>(
            (const float2*)d_in[0], l1, l2, l3, l4, out);
    }
}